// Round 1
// baseline (63.701 us; speedup 1.0000x reference)
//
#include <hip/hip_runtime.h>

// Problem constants (match the reference)
#define BATCH 64
#define FDIM  16
#define NDIM  128
#define FP    32
#define NEDGE (NDIM * (NDIM - 1))   // 16256
#define NEDGE4 (NEDGE / 4)          // 4064  (NEDGE % 4 == 0)

// out[b,e] = s1[b, recv[e]] + s2[b, send[e]]
//   s1[b,n] = sum_f x[b,f,n] * v1[f],  v1[f] = sum_g a[g]      * w[g,f]
//   s2[b,n] = sum_f x[b,f,n] * v2[f],  v2[f] = sum_g a[FP + g] * w[g,f]
__global__ __launch_bounds__(256) void gat_edge_fused(
    const float* __restrict__ x,     // (B, F, N)
    const float* __restrict__ w,     // (FP, F)
    const float* __restrict__ a,     // (2*FP)
    const int*   __restrict__ recv,  // (NEDGE)
    const int*   __restrict__ send,  // (NEDGE)
    float*       __restrict__ out)   // (B, NEDGE)
{
    __shared__ float v1s[FDIM];
    __shared__ float v2s[FDIM];
    __shared__ float s1s[NDIM];
    __shared__ float s2s[NDIM];

    const int b = blockIdx.y;
    const int t = threadIdx.x;

    // Phase 1: fold a into w -> v1, v2 (32 threads, 32 MACs each)
    if (t < 2 * FDIM) {
        const int f = t & (FDIM - 1);
        const float* av = a + ((t < FDIM) ? 0 : FP);
        float acc = 0.f;
#pragma unroll
        for (int g = 0; g < FP; ++g)
            acc += av[g] * w[g * FDIM + f];
        if (t < FDIM) v1s[f] = acc;
        else          v2s[f] = acc;
    }
    __syncthreads();

    // Phase 2: per-node scores for this batch (128 threads, coalesced x reads)
    if (t < NDIM) {
        const float* xb = x + (size_t)b * FDIM * NDIM + t;
        float acc1 = 0.f, acc2 = 0.f;
#pragma unroll
        for (int f = 0; f < FDIM; ++f) {
            const float xv = xb[f * NDIM];
            acc1 += xv * v1s[f];
            acc2 += xv * v2s[f];
        }
        s1s[t] = acc1;
        s2s[t] = acc2;
    }
    __syncthreads();

    // Phase 3: gather-add over 4 edges per thread (int4 / float4)
    const int e4 = blockIdx.x * blockDim.x + t;
    if (e4 < NEDGE4) {
        const int4 r = ((const int4*)recv)[e4];
        const int4 s = ((const int4*)send)[e4];
        float4 o;
        o.x = s1s[r.x] + s2s[s.x];
        o.y = s1s[r.y] + s2s[s.y];
        o.z = s1s[r.z] + s2s[s.z];
        o.w = s1s[r.w] + s2s[s.w];
        ((float4*)(out + (size_t)b * NEDGE))[e4] = o;
    }
}

extern "C" void kernel_launch(void* const* d_in, const int* in_sizes, int n_in,
                              void* d_out, int out_size, void* d_ws, size_t ws_size,
                              hipStream_t stream) {
    const float* x    = (const float*)d_in[0];
    const float* w    = (const float*)d_in[1];
    const float* a    = (const float*)d_in[2];
    const int*   recv = (const int*)d_in[3];
    const int*   send = (const int*)d_in[4];
    float*       out  = (float*)d_out;

    dim3 grid((NEDGE4 + 255) / 256, BATCH);  // (16, 64) = 1024 blocks
    gat_edge_fused<<<grid, 256, 0, stream>>>(x, w, a, recv, send, out);
}